// Round 2
// baseline (19.381 us; speedup 1.0000x reference)
//
#include <hip/hip_runtime.h>

#define WORD_LEN 16
#define BLOCK 256

__global__ __launch_bounds__(BLOCK) void oct_word_emb_kernel(
    const int* __restrict__ ids,
    const float* __restrict__ emb,
    float* __restrict__ out)
{
    // Embedding imag parts (cols 1..7), row stride 7.
    // Odd stride => (7*id + c) % 32 is a bijection mod 32 => random-id gathers
    // spread over all 32 banks (~2 lanes/bank avg).
    __shared__ float semb[256 * 7];
    // Output staging for coalesced stores: [word][comp] flat == output layout.
    __shared__ float sout[BLOCK * 7];

    const int tid = threadIdx.x;

    // Stage: thread t handles embedding row t (vocab = 256 = blockDim).
    {
        const float4* e4 = reinterpret_cast<const float4*>(emb);
        float4 lo = e4[tid * 2 + 0];   // emb[t][0..3]
        float4 hi = e4[tid * 2 + 1];   // emb[t][4..7]
        float* d = &semb[tid * 7];
        d[0] = lo.y; d[1] = lo.z; d[2] = lo.w;                // imag 1..3
        d[3] = hi.x; d[4] = hi.y; d[5] = hi.z; d[6] = hi.w;   // imag 4..7
    }
    __syncthreads();

    const long long b = (long long)blockIdx.x * BLOCK + tid;

    // 16 ids, 64B/thread via 4x int4 (L1 absorbs the 4x line re-touch).
    const int4* id4 = reinterpret_cast<const int4*>(ids + b * WORD_LEN);
    const int4 w0 = id4[0], w1 = id4[1], w2 = id4[2], w3 = id4[3];
    const int id[16] = {w0.x, w0.y, w0.z, w0.w,  w1.x, w1.y, w1.z, w1.w,
                        w2.x, w2.y, w2.z, w2.w,  w3.x, w3.y, w3.z, w3.w};

    float v[7];
    {
        const float* r0 = &semb[id[0] * 7];
        #pragma unroll
        for (int c = 0; c < 7; ++c) v[c] = r0[c];
    }

    // Fano triples (0-indexed). cross(a,b) per triple (i,j,k):
    //   r[k] += a[i]b[j] - a[j]b[i];  r[i] += a[j]b[k] - a[k]b[j];  r[j] += a[k]b[i] - a[i]b[k]
    #pragma unroll
    for (int t = 1; t < WORD_LEN; ++t) {
        const float* xr = &semb[id[t] * 7];
        float x[7];
        #pragma unroll
        for (int c = 0; c < 7; ++c) x[c] = xr[c];

        float r[7] = {0.f, 0.f, 0.f, 0.f, 0.f, 0.f, 0.f};
        constexpr int TRI[7][3] = {{0,1,2},{0,3,4},{0,6,5},{1,3,5},{1,4,6},{2,3,6},{2,5,4}};
        #pragma unroll
        for (int q = 0; q < 7; ++q) {
            const int i = TRI[q][0], j = TRI[q][1], k = TRI[q][2];
            r[k] = fmaf(v[i], x[j], r[k]);  r[k] = fmaf(-v[j], x[i], r[k]);
            r[i] = fmaf(v[j], x[k], r[i]);  r[i] = fmaf(-v[k], x[j], r[i]);
            r[j] = fmaf(v[k], x[i], r[j]);  r[j] = fmaf(-v[i], x[k], r[j]);
        }
        #pragma unroll
        for (int c = 0; c < 7; ++c) v[c] = r[c];
    }

    // Stage result: stride-7 write => (7t+c)%32 hits each bank exactly twice
    // per wave (2-way = free, m136).
    {
        float* d = &sout[tid * 7];
        #pragma unroll
        for (int c = 0; c < 7; ++c) d[c] = v[c];
    }
    __syncthreads();

    // Coalesced block store: 256 words * 7 floats = 448 float4s, contiguous.
    {
        const float4* so4 = reinterpret_cast<const float4*>(sout);
        float4* o4 = reinterpret_cast<float4*>(out + (size_t)blockIdx.x * BLOCK * 7);
        o4[tid] = so4[tid];
        if (tid < 192) o4[256 + tid] = so4[256 + tid];
    }
}

extern "C" void kernel_launch(void* const* d_in, const int* in_sizes, int n_in,
                              void* d_out, int out_size, void* d_ws, size_t ws_size,
                              hipStream_t stream) {
    const int* ids = (const int*)d_in[0];      // (524288, 16) int32
    const float* emb = (const float*)d_in[1];  // (256, 8) fp32
    float* out = (float*)d_out;                // (524288, 7) fp32

    const int batch = in_sizes[0] / WORD_LEN;  // 524288
    const int grid = batch / BLOCK;            // 2048

    oct_word_emb_kernel<<<grid, BLOCK, 0, stream>>>(ids, emb, out);
}

// Round 3
// 19.344 us; speedup vs baseline: 1.0019x; 1.0019x over previous
//
#include <hip/hip_runtime.h>

#define WORD_LEN 16
#define BLOCK 256

// (256, 8): cap VGPRs at 64 -> 8 waves/SIMD. Without it the fully-unrolled
// gather hoists ~112 LDS dwords into registers, VGPR >128, occupancy falls
// to 2 waves/SIMD and the kernel goes latency-bound (theory for the 19 us).
__global__ __launch_bounds__(BLOCK, 8) void oct_word_emb_kernel(
    const int* __restrict__ ids,
    const float* __restrict__ emb,
    float* __restrict__ out)
{
    // Embedding imag parts (cols 1..7), row stride 7.
    // Odd stride => (7*id + c) % 32 is a bijection mod 32 => random-id gathers
    // spread over all 32 banks (~2 lanes/bank avg).
    __shared__ float semb[256 * 7];
    // Output staging for coalesced stores: [word][comp] flat == output layout.
    __shared__ float sout[BLOCK * 7];

    const int tid = threadIdx.x;

    // Stage: thread t handles embedding row t (vocab = 256 = blockDim).
    {
        const float4* e4 = reinterpret_cast<const float4*>(emb);
        float4 lo = e4[tid * 2 + 0];   // emb[t][0..3]
        float4 hi = e4[tid * 2 + 1];   // emb[t][4..7]
        float* d = &semb[tid * 7];
        d[0] = lo.y; d[1] = lo.z; d[2] = lo.w;                // imag 1..3
        d[3] = hi.x; d[4] = hi.y; d[5] = hi.z; d[6] = hi.w;   // imag 4..7
    }
    __syncthreads();

    const long long b = (long long)blockIdx.x * BLOCK + tid;

    // 16 ids, 64B/thread via 4x int4 (L1 absorbs the 4x line re-touch).
    const int4* id4 = reinterpret_cast<const int4*>(ids + b * WORD_LEN);
    const int4 w0 = id4[0], w1 = id4[1], w2 = id4[2], w3 = id4[3];
    const int id[16] = {w0.x, w0.y, w0.z, w0.w,  w1.x, w1.y, w1.z, w1.w,
                        w2.x, w2.y, w2.z, w2.w,  w3.x, w3.y, w3.z, w3.w};

    float v[7];
    {
        const float* r0 = &semb[id[0] * 7];
        #pragma unroll
        for (int c = 0; c < 7; ++c) v[c] = r0[c];
    }

    // Fano triples (0-indexed). cross(a,b) per triple (i,j,k):
    //   r[k] += a[i]b[j] - a[j]b[i];  r[i] += a[j]b[k] - a[k]b[j];  r[j] += a[k]b[i] - a[i]b[k]
    #pragma unroll
    for (int t = 1; t < WORD_LEN; ++t) {
        const float* xr = &semb[id[t] * 7];
        float x[7];
        #pragma unroll
        for (int c = 0; c < 7; ++c) x[c] = xr[c];

        float r[7] = {0.f, 0.f, 0.f, 0.f, 0.f, 0.f, 0.f};
        constexpr int TRI[7][3] = {{0,1,2},{0,3,4},{0,6,5},{1,3,5},{1,4,6},{2,3,6},{2,5,4}};
        #pragma unroll
        for (int q = 0; q < 7; ++q) {
            const int i = TRI[q][0], j = TRI[q][1], k = TRI[q][2];
            r[k] = fmaf(v[i], x[j], r[k]);  r[k] = fmaf(-v[j], x[i], r[k]);
            r[i] = fmaf(v[j], x[k], r[i]);  r[i] = fmaf(-v[k], x[j], r[i]);
            r[j] = fmaf(v[k], x[i], r[j]);  r[j] = fmaf(-v[i], x[k], r[j]);
        }
        #pragma unroll
        for (int c = 0; c < 7; ++c) v[c] = r[c];
    }

    // Stage result: stride-7 write => (7t+c)%32 hits each bank exactly twice
    // per wave (2-way = free, m136).
    {
        float* d = &sout[tid * 7];
        #pragma unroll
        for (int c = 0; c < 7; ++c) d[c] = v[c];
    }
    __syncthreads();

    // Coalesced block store: 256 words * 7 floats = 448 float4s, contiguous.
    {
        const float4* so4 = reinterpret_cast<const float4*>(sout);
        float4* o4 = reinterpret_cast<float4*>(out + (size_t)blockIdx.x * BLOCK * 7);
        o4[tid] = so4[tid];
        if (tid < 192) o4[256 + tid] = so4[256 + tid];
    }
}

extern "C" void kernel_launch(void* const* d_in, const int* in_sizes, int n_in,
                              void* d_out, int out_size, void* d_ws, size_t ws_size,
                              hipStream_t stream) {
    const int* ids = (const int*)d_in[0];      // (524288, 16) int32
    const float* emb = (const float*)d_in[1];  // (256, 8) fp32
    float* out = (float*)d_out;                // (524288, 7) fp32

    const int batch = in_sizes[0] / WORD_LEN;  // 524288
    const int grid = batch / BLOCK;            // 2048

    oct_word_emb_kernel<<<grid, BLOCK, 0, stream>>>(ids, emb, out);
}

// Round 4
// 17.444 us; speedup vs baseline: 1.1110x; 1.1089x over previous
//
#include <hip/hip_runtime.h>

#define WORD_LEN 16
#define BLOCK 256

// (256, 8): keep >=8 waves/SIMD for TLP latency hiding; live state ~54 VGPRs.
__global__ __launch_bounds__(BLOCK, 8) void oct_word_emb_kernel(
    const int* __restrict__ ids,
    const float* __restrict__ emb,
    float* __restrict__ out)
{
    // Gather layout: two float4 arrays, 16B row stride.
    // Row-start bank = 4*(id%8) -> 8 quad-bank groups; 64 random lanes spread
    // ~8/group -> ds_read_b128 runs near its 8-pass floor (vs 112 b32 reads
    // at ~9.5 cyc each in rounds 0-3 = ~14us/CU of LDS-pipe serialization).
    __shared__ float4 slo[256];   // imag 0..3  (emb cols 1..4)
    __shared__ float4 shi[256];   // imag 4..6  (emb cols 5..7) + pad
    __shared__ float sout[BLOCK * 7];

    const int tid = threadIdx.x;

    // Stage embedding: thread t handles row t (vocab = 256 = blockDim).
    {
        const float4* e4 = reinterpret_cast<const float4*>(emb);
        float4 lo = e4[tid * 2 + 0];   // emb[t][0..3]
        float4 hi = e4[tid * 2 + 1];   // emb[t][4..7]
        slo[tid] = make_float4(lo.y, lo.z, lo.w, hi.x);   // imag 1..4
        shi[tid] = make_float4(hi.y, hi.z, hi.w, 0.0f);   // imag 5..7
    }
    __syncthreads();

    const long long b = (long long)blockIdx.x * BLOCK + tid;

    // 16 ids, 64B/thread via 4x int4 (unchanged this round).
    const int4* id4 = reinterpret_cast<const int4*>(ids + b * WORD_LEN);
    const int4 w0 = id4[0], w1 = id4[1], w2 = id4[2], w3 = id4[3];
    const int id[16] = {w0.x, w0.y, w0.z, w0.w,  w1.x, w1.y, w1.z, w1.w,
                        w2.x, w2.y, w2.z, w2.w,  w3.x, w3.y, w3.z, w3.w};

    float v[7];
    {
        const float4 a = slo[id[0]];
        const float4 h = shi[id[0]];
        v[0] = a.x; v[1] = a.y; v[2] = a.z; v[3] = a.w;
        v[4] = h.x; v[5] = h.y; v[6] = h.z;
    }

    // Fano triples (0-indexed). cross(a,b) per triple (i,j,k):
    //   r[k] += a[i]b[j] - a[j]b[i];  r[i] += a[j]b[k] - a[k]b[j];  r[j] += a[k]b[i] - a[i]b[k]
    #pragma unroll
    for (int t = 1; t < WORD_LEN; ++t) {
        const float4 a = slo[id[t]];
        const float4 h = shi[id[t]];
        const float x[7] = {a.x, a.y, a.z, a.w, h.x, h.y, h.z};

        float r[7] = {0.f, 0.f, 0.f, 0.f, 0.f, 0.f, 0.f};
        constexpr int TRI[7][3] = {{0,1,2},{0,3,4},{0,6,5},{1,3,5},{1,4,6},{2,3,6},{2,5,4}};
        #pragma unroll
        for (int q = 0; q < 7; ++q) {
            const int i = TRI[q][0], j = TRI[q][1], k = TRI[q][2];
            r[k] = fmaf(v[i], x[j], r[k]);  r[k] = fmaf(-v[j], x[i], r[k]);
            r[i] = fmaf(v[j], x[k], r[i]);  r[i] = fmaf(-v[k], x[j], r[i]);
            r[j] = fmaf(v[k], x[i], r[j]);  r[j] = fmaf(-v[i], x[k], r[j]);
        }
        #pragma unroll
        for (int c = 0; c < 7; ++c) v[c] = r[c];
    }

    // Stage result: stride-7 write => 2 lanes/bank (free), then coalesced store.
    {
        float* d = &sout[tid * 7];
        #pragma unroll
        for (int c = 0; c < 7; ++c) d[c] = v[c];
    }
    __syncthreads();

    {
        const float4* so4 = reinterpret_cast<const float4*>(sout);
        float4* o4 = reinterpret_cast<float4*>(out + (size_t)blockIdx.x * BLOCK * 7);
        o4[tid] = so4[tid];
        if (tid < 192) o4[256 + tid] = so4[256 + tid];
    }
}

extern "C" void kernel_launch(void* const* d_in, const int* in_sizes, int n_in,
                              void* d_out, int out_size, void* d_ws, size_t ws_size,
                              hipStream_t stream) {
    const int* ids = (const int*)d_in[0];      // (524288, 16) int32
    const float* emb = (const float*)d_in[1];  // (256, 8) fp32
    float* out = (float*)d_out;                // (524288, 7) fp32

    const int batch = in_sizes[0] / WORD_LEN;  // 524288
    const int grid = batch / BLOCK;            // 2048

    oct_word_emb_kernel<<<grid, BLOCK, 0, stream>>>(ids, emb, out);
}